// Round 9
// baseline (211.273 us; speedup 1.0000x reference)
//
#include <hip/hip_runtime.h>
#include <hip/hip_bf16.h>
#include <math.h>

// B=2, T=2048, C=1024, H=16, D=64
typedef __attribute__((ext_vector_type(8))) short s8v;    // 8 bf16
typedef __attribute__((ext_vector_type(4))) float f4v;    // 4 fp32
typedef __attribute__((ext_vector_type(16))) float f16v;  // 16 fp32 (32x32 C/D)
typedef unsigned short ush;
typedef unsigned int u32;

#define QSCALE 0.180336880f   /* 0.125 * log2(e): S emerges in log2 domain */

static __device__ __forceinline__ ush f2bf(float f) {
    u32 x = __builtin_bit_cast(u32, f);
    return (ush)((x + 0x7fffu + ((x >> 16) & 1u)) >> 16);
}
static __device__ __forceinline__ u32 bfpack(float lo, float hi) {
    u32 a = __builtin_bit_cast(u32, lo) + 0x8000u;
    u32 b = __builtin_bit_cast(u32, hi) + 0x8000u;
    return __builtin_amdgcn_perm(b, a, 0x07060302);
}
static __device__ __forceinline__ void gl_lds16(const void* g, void* l) {
    __builtin_amdgcn_global_load_lds(
        (const __attribute__((address_space(1))) u32*)g,
        (__attribute__((address_space(3))) u32*)l, 16, 0, 0);
}
#if __has_builtin(__builtin_amdgcn_exp2f)
#define EXP2F(x) __builtin_amdgcn_exp2f(x)
#else
#define EXP2F(x) exp2f(x)
#endif

// ---------------------------------------------------------------------------
// Prep (fused): blocks [0,512): Wt[n][k] = bf16(W[k][n]);
//   blocks [512,1536): Vf fragment layout: elem (bh, key, d) ->
//   Vf[(bh*32 + key>>6)*4096 + ((key&63)>>3)*512 + d*8 + (key&7)].
// ---------------------------------------------------------------------------
__global__ __launch_bounds__(256) void prep_kernel(
    const float* __restrict__ W, const float* __restrict__ XV,
    ush* __restrict__ Wt, ush* __restrict__ Vf)
{
    __shared__ float Ts[64][68];
    const int tid = threadIdx.x;
    const int bid = blockIdx.x;
    if (bid < 512) {
        const int n0 = (bid & 31) * 64, k0 = (bid >> 5) * 64;
        #pragma unroll
        for (int p = 0; p < 4; ++p) {
            const int idx = p * 256 + tid;
            const int kr = idx >> 4, nc4 = idx & 15;
            float4 v = *(const float4*)(W + (size_t)(k0 + kr) * 2048 + n0 + nc4 * 4);
            Ts[kr][nc4 * 4 + 0] = v.x; Ts[kr][nc4 * 4 + 1] = v.y;
            Ts[kr][nc4 * 4 + 2] = v.z; Ts[kr][nc4 * 4 + 3] = v.w;
        }
        __syncthreads();
        const int n = tid >> 2, kb = (tid & 3) * 16;
        #pragma unroll
        for (int p = 0; p < 4; ++p) {
            const int k = kb + p * 4;
            ushort4 o;
            o.x = f2bf(Ts[k + 0][n]); o.y = f2bf(Ts[k + 1][n]);
            o.z = f2bf(Ts[k + 2][n]); o.w = f2bf(Ts[k + 3][n]);
            *(ushort4*)(Wt + (size_t)(n0 + n) * 1024 + k0 + k) = o;
        }
    } else {
        const int id = bid - 512;
        const int kt = id & 31, bh = id >> 5;       // key-tile, head
        const int t0 = kt * 64;
        const int b = bh >> 4, h = bh & 15;
        #pragma unroll
        for (int p = 0; p < 4; ++p) {
            const int idx = p * 256 + tid;
            const int tr = idx >> 4, dc4 = idx & 15;
            float4 v = *(const float4*)(XV + (size_t)(b * 2048 + t0 + tr) * 1024
                                        + h * 64 + dc4 * 4);
            Ts[tr][dc4 * 4 + 0] = v.x; Ts[tr][dc4 * 4 + 1] = v.y;
            Ts[tr][dc4 * 4 + 2] = v.z; Ts[tr][dc4 * 4 + 3] = v.w;
        }
        __syncthreads();
        ush* Vtile = Vf + ((size_t)bh * 32 + kt) * 4096;
        const int d = tid >> 2, tb = (tid & 3) * 16;
        #pragma unroll
        for (int p = 0; p < 4; ++p) {
            const int tq = tb + p * 4;              // 0..63, tq&7 in {0,4}
            ushort4 o;
            o.x = f2bf(Ts[tq + 0][d]); o.y = f2bf(Ts[tq + 1][d]);
            o.z = f2bf(Ts[tq + 2][d]); o.w = f2bf(Ts[tq + 3][d]);
            *(ushort4*)(Vtile + (tq >> 3) * 512 + d * 8 + (tq & 7)) = o;
        }
    }
}

// ---------------------------------------------------------------------------
// MFMA GEMM: C = bf16(X) @ Wt^T + bias.  128x128 tile, BK=32 (R5 structure).
//   Q -> Qb row-major [bh][t][d], scaled by 0.125*log2e.
//   K -> Kf fragment layout [bh][kt][ch=d>>3][t&63][d&7].
// ---------------------------------------------------------------------------
__global__ __launch_bounds__(256) void gemm_kernel(
    const float* __restrict__ X, const ush* __restrict__ Wt,
    const float* __restrict__ bias,
    ush* __restrict__ Qb, ush* __restrict__ Kf)
{
    __shared__ ush As[128 * 40];   // [m][k] stride 40 (80 B = 5x16 B)
    __shared__ ush Bs[128 * 32];   // [n][k] unpadded (DMA layout)

    const int tid = threadIdx.x;
    const int wid = tid >> 6, lane = tid & 63;
    const int quad = lane >> 4, l15 = lane & 15;
    const int wm = wid >> 1, wn = wid & 1;
    const int m0 = blockIdx.y * 128, n0 = blockIdx.x * 128;

    const int arow = tid >> 1;          // 0..127
    const int akc = (tid & 1) * 16;     // 0 or 16
    const int brow = lane >> 2;
    const int bkk = (lane & 3) * 8;
    const size_t brow_g = (size_t)(n0 + wid * 32 + brow);
    ush* BsW = &Bs[wid * 1024];

    f4v acc[4][4];
    #pragma unroll
    for (int i = 0; i < 4; ++i)
        #pragma unroll
        for (int j = 0; j < 4; ++j) acc[i][j] = (f4v){0.f, 0.f, 0.f, 0.f};

    for (int k0 = 0; k0 < 1024; k0 += 32) {
        gl_lds16(Wt + brow_g * 1024 + k0 + bkk, BsW);
        gl_lds16(Wt + (brow_g + 16) * 1024 + k0 + bkk, BsW + 512);
        {
            const float* xp = X + (size_t)(m0 + arow) * 1024 + k0 + akc;
            float4 f0 = ((const float4*)xp)[0];
            float4 f1 = ((const float4*)xp)[1];
            float4 f2 = ((const float4*)xp)[2];
            float4 f3 = ((const float4*)xp)[3];
            uint4 w0, w1;
            w0.x = bfpack(f0.x, f0.y); w0.y = bfpack(f0.z, f0.w);
            w0.z = bfpack(f1.x, f1.y); w0.w = bfpack(f1.z, f1.w);
            w1.x = bfpack(f2.x, f2.y); w1.y = bfpack(f2.z, f2.w);
            w1.z = bfpack(f3.x, f3.y); w1.w = bfpack(f3.z, f3.w);
            *(uint4*)&As[arow * 40 + akc] = w0;
            *(uint4*)&As[arow * 40 + akc + 8] = w1;
        }
        __syncthreads();

        s8v a[4], bf[4];
        #pragma unroll
        for (int i = 0; i < 4; ++i)
            a[i] = *(const s8v*)&As[(wm * 64 + i * 16 + l15) * 40 + quad * 8];
        #pragma unroll
        for (int j = 0; j < 4; ++j)
            bf[j] = *(const s8v*)&Bs[(wn * 64 + j * 16 + l15) * 32 + quad * 8];
        #pragma unroll
        for (int i = 0; i < 4; ++i)
            #pragma unroll
            for (int j = 0; j < 4; ++j)
                acc[i][j] = __builtin_amdgcn_mfma_f32_16x16x32_bf16(
                    a[i], bf[j], acc[i][j], 0, 0, 0);
        __syncthreads();
    }

    #pragma unroll
    for (int j = 0; j < 4; ++j) {
        const int n = n0 + wn * 64 + j * 16 + l15;
        const float bv = bias[n];
        const bool is_k = n >= 1024;
        const int nn = n & 1023;
        const int h = nn >> 6, d = nn & 63;
        #pragma unroll
        for (int i = 0; i < 4; ++i) {
            const int mrow = m0 + wm * 64 + i * 16 + quad * 4;
            #pragma unroll
            for (int r = 0; r < 4; ++r) {
                const int m = mrow + r;
                const int b = m >> 11, t = m & 2047;
                const int bh = b * 16 + h;
                float val = acc[i][j][r] + bv;
                if (is_k) {
                    Kf[((size_t)bh * 32 + (t >> 6)) * 4096
                       + (d >> 3) * 512 + (t & 63) * 8 + (d & 7)] = f2bf(val);
                } else {
                    Qb[((size_t)bh * 2048 + t) * 64 + d] = f2bf(val * QSCALE);
                }
            }
        }
    }
}

// ---------------------------------------------------------------------------
// Barrier-free MFMA causal flash attention.  ONE WAVE per block (64 thr),
//   32 q-rows per wave.  32x32x16 MFMA, S^T form (lane column q = lane&31).
//   K/V fragments loaded DIRECTLY global->VGPR from fragment-order arrays
//   (coalesced dwordx4, L2-resident).  P stays in registers (shfl_xor 32
//   half-swap builds the PV B-frag).  No __syncthreads anywhere.
//   LDS: wave-private 8.5 KB output transpose only.
//   Grid 2048 = (qt heavy-first, half, bh).
// ---------------------------------------------------------------------------
__global__ __launch_bounds__(64, 4) void attn_kernel(
    const ush* __restrict__ Qb, const ush* __restrict__ Kf,
    const ush* __restrict__ Vf, float* __restrict__ Y)
{
    __shared__ float LT[32 * 68];          // 8704 B, wave-private

    const int lane = threadIdx.x;
    const int l31 = lane & 31, hi = lane >> 5;

    const int idx = blockIdx.x;
    const int bh = idx & 31, v = idx >> 5;       // v in 0..63
    const int qt = 31 - (v >> 1);                // heavy tiles dispatch first
    const int half = v & 1;
    const int b = bh >> 4, h = bh & 15;
    const int q0 = qt * 64 + half * 32;

    const ush* Qg = Qb + (size_t)bh * 2048 * 64;
    const ush* Kbh = Kf + (size_t)bh * 32 * 4096;
    const ush* Vbh = Vf + (size_t)bh * 32 * 4096;

    // ---- Q B-frags: lane l31 = q row, chunk (2s+hi). Direct (gather) loads.
    s8v bq[4];
    #pragma unroll
    for (int s = 0; s < 4; ++s)
        bq[s] = *(const s8v*)(Qg + (size_t)(q0 + l31) * 64 + ((s << 1) + hi) * 8);

    f16v acco0 = {}, acco1 = {};
    float mr = -INFINITY, lr = 0.f;
    const int qg = q0 + l31;                     // lane's q row (global)

    for (int kt = 0; kt <= qt; ++kt) {
        const ush* Kt = Kbh + (size_t)kt * 4096;
        const ush* Vt = Vbh + (size_t)kt * 4096;
        // upper 32-key subtile fully masked on the diagonal of half 0
        const bool do1 = !(kt == qt && half == 0);

        // S^T = K Q^T : rows=keys (2 subtiles of 32), col=q=l31
        f16v s0 = {}, s1 = {};
        #pragma unroll
        for (int s = 0; s < 4; ++s) {
            const int ch = (s << 1) + hi;
            s8v ak0 = *(const s8v*)(Kt + ch * 512 + l31 * 8);
            s0 = __builtin_amdgcn_mfma_f32_32x32x16_bf16(ak0, bq[s], s0, 0, 0, 0);
        }
        if (do1) {
            #pragma unroll
            for (int s = 0; s < 4; ++s) {
                const int ch = (s << 1) + hi;
                s8v ak1 = *(const s8v*)(Kt + ch * 512 + 256 + l31 * 8);
                s1 = __builtin_amdgcn_mfma_f32_32x32x16_bf16(ak1, bq[s], s1, 0, 0, 0);
            }
        }

        // causal mask (diag tile only) + running max
        float mloc = -INFINITY;
        if (kt == qt) {
            #pragma unroll
            for (int r = 0; r < 16; ++r) {
                const int keyb = kt * 64 + (r & 3) + 8 * (r >> 2) + 4 * hi;
                float v0 = (keyb > qg) ? -INFINITY : s0[r];
                s0[r] = v0;
                mloc = fmaxf(mloc, v0);
                if (do1) {
                    float v1 = (keyb + 32 > qg) ? -INFINITY : s1[r];
                    s1[r] = v1;
                    mloc = fmaxf(mloc, v1);
                }
            }
        } else {
            #pragma unroll
            for (int r = 0; r < 16; ++r)
                mloc = fmaxf(mloc, fmaxf(s0[r], s1[r]));
        }
        mloc = fmaxf(mloc, __shfl_xor(mloc, 32));
        const float mnew = fmaxf(mr, mloc);
        const float alpha = EXP2F(mr - mnew);
        mr = mnew;

        // exp2 + row sum + bf16 pack (pairs of consecutive keys)
        float ps = 0.f;
        u32 P0[8], P1[8];
        #pragma unroll
        for (int p = 0; p < 8; ++p) {
            float a0 = EXP2F(s0[2 * p] - mnew), b0 = EXP2F(s0[2 * p + 1] - mnew);
            ps += a0 + b0;
            P0[p] = bfpack(a0, b0);
        }
        if (do1) {
            #pragma unroll
            for (int p = 0; p < 8; ++p) {
                float a1 = EXP2F(s1[2 * p] - mnew), b1 = EXP2F(s1[2 * p + 1] - mnew);
                ps += a1 + b1;
                P1[p] = bfpack(a1, b1);
            }
        }
        ps += __shfl_xor(ps, 32);
        lr = lr * alpha + ps;

        #pragma unroll
        for (int r = 0; r < 16; ++r) { acco0[r] *= alpha; acco1[r] *= alpha; }

        // O^T += V^T P^T.  B-frag(P^T) built in-register: lane half swap.
        const int tmax = do1 ? 2 : 1;
        for (int t = 0; t < tmax; ++t) {
            const u32* pt = t ? P1 : P0;
            #pragma unroll
            for (int ss = 0; ss < 2; ++ss) {
                const int b4 = ss * 4;
                const u32 x0 = __shfl_xor(pt[b4 + 0], 32);
                const u32 x1 = __shfl_xor(pt[b4 + 1], 32);
                const u32 x2 = __shfl_xor(pt[b4 + 2], 32);
                const u32 x3 = __shfl_xor(pt[b4 + 3], 32);
                uint4 fr;
                fr.x = hi ? x2 : pt[b4 + 0];
                fr.y = hi ? x3 : pt[b4 + 1];
                fr.z = hi ? pt[b4 + 2] : x0;
                fr.w = hi ? pt[b4 + 3] : x1;
                const s8v pf = __builtin_bit_cast(s8v, fr);
                const int sg = t * 2 + ss, ch = (sg << 1) + hi;
                s8v av0 = *(const s8v*)(Vt + ch * 512 + l31 * 8);
                s8v av1 = *(const s8v*)(Vt + ch * 512 + 256 + l31 * 8);
                acco0 = __builtin_amdgcn_mfma_f32_32x32x16_bf16(av0, pf, acco0, 0, 0, 0);
                acco1 = __builtin_amdgcn_mfma_f32_32x32x16_bf16(av1, pf, acco1, 0, 0, 0);
            }
        }
    }

    // ---- epilogue: wave-private LDS transpose -> coalesced float4 stores
    const float inv = 1.0f / lr;
    #pragma unroll
    for (int r = 0; r < 16; ++r) {
        const int d = (r & 3) + 8 * (r >> 2) + 4 * hi;
        LT[l31 * 68 + d] = acco0[r] * inv;
        LT[l31 * 68 + 32 + d] = acco1[r] * inv;
    }
    const int qr2 = lane >> 4, chk = lane & 15;
    #pragma unroll
    for (int p = 0; p < 8; ++p) {
        const int qrow = p * 4 + qr2;
        f4v v4 = *(const f4v*)&LT[qrow * 68 + chk * 4];
        *(float4*)(Y + (size_t)(b * 2048 + q0 + qrow) * 1024
                   + h * 64 + chk * 4) = (float4){v4[0], v4[1], v4[2], v4[3]};
    }
}

// ---------------------------------------------------------------------------
extern "C" void kernel_launch(void* const* d_in, const int* in_sizes, int n_in,
                              void* d_out, int out_size, void* d_ws,
                              size_t ws_size, hipStream_t stream)
{
    const float* x_qk = (const float*)d_in[0];
    const float* x_v  = (const float*)d_in[1];
    const float* W    = (const float*)d_in[2];
    const float* bias = (const float*)d_in[3];
    float* out = (float*)d_out;

    unsigned char* ws = (unsigned char*)d_ws;
    ush* Wt = (ush*)(ws);                  // 4 MB  [0,4M)
    ush* Vf = (ush*)(ws + (4u << 20));     // 8 MB  [4M,12M)
    ush* Qb = (ush*)(ws + (12u << 20));    // 8 MB  [12M,20M)
    ush* Kf = (ush*)(ws + (20u << 20));    // 8 MB  [20M,28M)

    prep_kernel<<<1536, 256, 0, stream>>>(W, x_v, Wt, Vf);
    gemm_kernel<<<dim3(16, 32), 256, 0, stream>>>(x_qk, Wt, bias, Qb, Kf);
    attn_kernel<<<2048, 64, 0, stream>>>(Qb, Kf, Vf, out);
}

// Round 10
// 173.710 us; speedup vs baseline: 1.2162x; 1.2162x over previous
//
#include <hip/hip_runtime.h>
#include <hip/hip_bf16.h>
#include <math.h>

// B=2, T=2048, C=1024, H=16, D=64
typedef __attribute__((ext_vector_type(8))) short s8v;    // 8 bf16
typedef __attribute__((ext_vector_type(4))) float f4v;    // 4 fp32
typedef __attribute__((ext_vector_type(16))) float f16v;  // 16 fp32 (32x32 C/D)
typedef unsigned short ush;
typedef unsigned int u32;

#define QSCALE 0.180336880f   /* 0.125 * log2(e): S emerges in log2 domain */

static __device__ __forceinline__ ush f2bf(float f) {
    u32 x = __builtin_bit_cast(u32, f);
    return (ush)((x + 0x7fffu + ((x >> 16) & 1u)) >> 16);
}
static __device__ __forceinline__ u32 bfpack(float lo, float hi) {
    u32 a = __builtin_bit_cast(u32, lo) + 0x8000u;
    u32 b = __builtin_bit_cast(u32, hi) + 0x8000u;
    return __builtin_amdgcn_perm(b, a, 0x07060302);
}
static __device__ __forceinline__ void gl_lds16(const void* g, void* l) {
    __builtin_amdgcn_global_load_lds(
        (const __attribute__((address_space(1))) u32*)g,
        (__attribute__((address_space(3))) u32*)l, 16, 0, 0);
}
#if __has_builtin(__builtin_amdgcn_exp2f)
#define EXP2F(x) __builtin_amdgcn_exp2f(x)
#else
#define EXP2F(x) exp2f(x)
#endif

// ---------------------------------------------------------------------------
// Prep (fused): blocks [0,512): Wt[n][k] = bf16(W[k][n]);
//   blocks [512,1536): Vf fragment layout: elem (bh, key, d) ->
//   Vf[(bh*32 + key>>6)*4096 + ((key&63)>>3)*512 + d*8 + (key&7)].
// ---------------------------------------------------------------------------
__global__ __launch_bounds__(256) void prep_kernel(
    const float* __restrict__ W, const float* __restrict__ XV,
    ush* __restrict__ Wt, ush* __restrict__ Vf)
{
    __shared__ float Ts[64][68];
    const int tid = threadIdx.x;
    const int bid = blockIdx.x;
    if (bid < 512) {
        const int n0 = (bid & 31) * 64, k0 = (bid >> 5) * 64;
        #pragma unroll
        for (int p = 0; p < 4; ++p) {
            const int idx = p * 256 + tid;
            const int kr = idx >> 4, nc4 = idx & 15;
            float4 v = *(const float4*)(W + (size_t)(k0 + kr) * 2048 + n0 + nc4 * 4);
            Ts[kr][nc4 * 4 + 0] = v.x; Ts[kr][nc4 * 4 + 1] = v.y;
            Ts[kr][nc4 * 4 + 2] = v.z; Ts[kr][nc4 * 4 + 3] = v.w;
        }
        __syncthreads();
        const int n = tid >> 2, kb = (tid & 3) * 16;
        #pragma unroll
        for (int p = 0; p < 4; ++p) {
            const int k = kb + p * 4;
            ushort4 o;
            o.x = f2bf(Ts[k + 0][n]); o.y = f2bf(Ts[k + 1][n]);
            o.z = f2bf(Ts[k + 2][n]); o.w = f2bf(Ts[k + 3][n]);
            *(ushort4*)(Wt + (size_t)(n0 + n) * 1024 + k0 + k) = o;
        }
    } else {
        const int id = bid - 512;
        const int kt = id & 31, bh = id >> 5;       // key-tile, head
        const int t0 = kt * 64;
        const int b = bh >> 4, h = bh & 15;
        #pragma unroll
        for (int p = 0; p < 4; ++p) {
            const int idx = p * 256 + tid;
            const int tr = idx >> 4, dc4 = idx & 15;
            float4 v = *(const float4*)(XV + (size_t)(b * 2048 + t0 + tr) * 1024
                                        + h * 64 + dc4 * 4);
            Ts[tr][dc4 * 4 + 0] = v.x; Ts[tr][dc4 * 4 + 1] = v.y;
            Ts[tr][dc4 * 4 + 2] = v.z; Ts[tr][dc4 * 4 + 3] = v.w;
        }
        __syncthreads();
        ush* Vtile = Vf + ((size_t)bh * 32 + kt) * 4096;
        const int d = tid >> 2, tb = (tid & 3) * 16;
        #pragma unroll
        for (int p = 0; p < 4; ++p) {
            const int tq = tb + p * 4;              // 0..63, tq&7 in {0,4}
            ushort4 o;
            o.x = f2bf(Ts[tq + 0][d]); o.y = f2bf(Ts[tq + 1][d]);
            o.z = f2bf(Ts[tq + 2][d]); o.w = f2bf(Ts[tq + 3][d]);
            *(ushort4*)(Vtile + (tq >> 3) * 512 + d * 8 + (tq & 7)) = o;
        }
    }
}

// ---------------------------------------------------------------------------
// MFMA GEMM: C = bf16(X) @ Wt^T + bias.  128x128 tile, BK=32.
//   Q -> Qb row-major [bh][t][d], scaled by 0.125*log2e.
//   K -> Kf fragment layout [bh][kt][ch=d>>3][t&63][d&7].
// ---------------------------------------------------------------------------
__global__ __launch_bounds__(256) void gemm_kernel(
    const float* __restrict__ X, const ush* __restrict__ Wt,
    const float* __restrict__ bias,
    ush* __restrict__ Qb, ush* __restrict__ Kf)
{
    __shared__ ush As[128 * 40];   // [m][k] stride 40 (80 B = 5x16 B)
    __shared__ ush Bs[128 * 32];   // [n][k] unpadded (DMA layout)

    const int tid = threadIdx.x;
    const int wid = tid >> 6, lane = tid & 63;
    const int quad = lane >> 4, l15 = lane & 15;
    const int wm = wid >> 1, wn = wid & 1;
    const int m0 = blockIdx.y * 128, n0 = blockIdx.x * 128;

    const int arow = tid >> 1;          // 0..127
    const int akc = (tid & 1) * 16;     // 0 or 16
    const int brow = lane >> 2;
    const int bkk = (lane & 3) * 8;
    const size_t brow_g = (size_t)(n0 + wid * 32 + brow);
    ush* BsW = &Bs[wid * 1024];

    f4v acc[4][4];
    #pragma unroll
    for (int i = 0; i < 4; ++i)
        #pragma unroll
        for (int j = 0; j < 4; ++j) acc[i][j] = (f4v){0.f, 0.f, 0.f, 0.f};

    for (int k0 = 0; k0 < 1024; k0 += 32) {
        gl_lds16(Wt + brow_g * 1024 + k0 + bkk, BsW);
        gl_lds16(Wt + (brow_g + 16) * 1024 + k0 + bkk, BsW + 512);
        {
            const float* xp = X + (size_t)(m0 + arow) * 1024 + k0 + akc;
            float4 f0 = ((const float4*)xp)[0];
            float4 f1 = ((const float4*)xp)[1];
            float4 f2 = ((const float4*)xp)[2];
            float4 f3 = ((const float4*)xp)[3];
            uint4 w0, w1;
            w0.x = bfpack(f0.x, f0.y); w0.y = bfpack(f0.z, f0.w);
            w0.z = bfpack(f1.x, f1.y); w0.w = bfpack(f1.z, f1.w);
            w1.x = bfpack(f2.x, f2.y); w1.y = bfpack(f2.z, f2.w);
            w1.z = bfpack(f3.x, f3.y); w1.w = bfpack(f3.z, f3.w);
            *(uint4*)&As[arow * 40 + akc] = w0;
            *(uint4*)&As[arow * 40 + akc + 8] = w1;
        }
        __syncthreads();

        s8v a[4], bf[4];
        #pragma unroll
        for (int i = 0; i < 4; ++i)
            a[i] = *(const s8v*)&As[(wm * 64 + i * 16 + l15) * 40 + quad * 8];
        #pragma unroll
        for (int j = 0; j < 4; ++j)
            bf[j] = *(const s8v*)&Bs[(wn * 64 + j * 16 + l15) * 32 + quad * 8];
        #pragma unroll
        for (int i = 0; i < 4; ++i)
            #pragma unroll
            for (int j = 0; j < 4; ++j)
                acc[i][j] = __builtin_amdgcn_mfma_f32_16x16x32_bf16(
                    a[i], bf[j], acc[i][j], 0, 0, 0);
        __syncthreads();
    }

    #pragma unroll
    for (int j = 0; j < 4; ++j) {
        const int n = n0 + wn * 64 + j * 16 + l15;
        const float bv = bias[n];
        const bool is_k = n >= 1024;
        const int nn = n & 1023;
        const int h = nn >> 6, d = nn & 63;
        #pragma unroll
        for (int i = 0; i < 4; ++i) {
            const int mrow = m0 + wm * 64 + i * 16 + quad * 4;
            #pragma unroll
            for (int r = 0; r < 4; ++r) {
                const int m = mrow + r;
                const int b = m >> 11, t = m & 2047;
                const int bh = b * 16 + h;
                float val = acc[i][j][r] + bv;
                if (is_k) {
                    Kf[((size_t)bh * 32 + (t >> 6)) * 4096
                       + (d >> 3) * 512 + (t & 63) * 8 + (d & 7)] = f2bf(val);
                } else {
                    Qb[((size_t)bh * 2048 + t) * 64 + d] = f2bf(val * QSCALE);
                }
            }
        }
    }
}

// ---------------------------------------------------------------------------
// Split-KEY barrier-free MFMA causal flash attention.
//   Block = 128 thr = 2 waves, both on the SAME 32 q-rows; wave0 takes
//   kt in [0, n/2) (never masked), wave1 takes [n/2, qt] (owns diagonal).
//   Loops are barrier-free: K/V frags loaded directly global->VGPR from
//   fragment-order arrays (coalesced dwordx4, L2-resident); P stays in
//   registers (shfl_xor-32 half swap). ONE __syncthreads at the end:
//   wave1 deposits (O1,m1,l1) in LDS, wave0 does the exact flash-merge.
//   Grid 2048 -> 4096 waves = 4/SIMD. CU-balanced u=(2qt+half) pairing.
// ---------------------------------------------------------------------------
__global__ __launch_bounds__(128, 4) void attn_kernel(
    const ush* __restrict__ Qb, const ush* __restrict__ Kf,
    const ush* __restrict__ Vf, float* __restrict__ Y)
{
    __shared__ float MO[64 * 32];      // wave1 partial O (per-lane 32 f32)
    __shared__ float MS[128];          // [lane]=m1, [64+lane]=l1
    __shared__ float LT[32 * 68];      // output transpose (wave0)

    const int tid = threadIdx.x;
    const int w = tid >> 6, lane = tid & 63;
    const int l31 = lane & 31, hi = lane >> 5;

    // CU-balanced schedule: same-CU slots (idx +- 256k) get u pairs (u,63-u)
    const int idx = blockIdx.x;
    const int rr = idx >> 8, ii = idx & 255;
    const int bh = ii >> 3, s_ = ii & 7;
    const int w_ = s_ * 4 + (rr >> 1);
    const int u = (rr & 1) ? (63 - w_) : w_;
    const int qt = u >> 1, half = u & 1;
    const int b = bh >> 4, h = bh & 15;
    const int q0 = qt * 64 + half * 32;

    const int n = qt + 1, nh = n >> 1;
    const int kt_lo = w ? nh : 0;
    const int kt_end = w ? n : nh;

    const ush* Qg = Qb + (size_t)bh * 2048 * 64;
    const ush* Kbh = Kf + (size_t)bh * 32 * 4096;
    const ush* Vbh = Vf + (size_t)bh * 32 * 4096;

    // ---- Q B-frags: lane l31 = q row, chunk (2s+hi)
    s8v bq[4];
    #pragma unroll
    for (int s = 0; s < 4; ++s)
        bq[s] = *(const s8v*)(Qg + (size_t)(q0 + l31) * 64 + ((s << 1) + hi) * 8);

    f16v acco0 = {}, acco1 = {};
    float mr = -INFINITY, lr = 0.f;
    const int qg = q0 + l31;                     // lane's q row (global)

    for (int kt = kt_lo; kt < kt_end; ++kt) {
        const ush* Kt = Kbh + (size_t)kt * 4096;
        const ush* Vt = Vbh + (size_t)kt * 4096;
        const bool diag = (kt == qt);            // only reachable in wave1
        const bool do1 = !(diag && half == 0);

        // S^T = K Q^T : rows=keys (2 subtiles of 32), col=q=l31
        f16v s0 = {}, s1 = {};
        #pragma unroll
        for (int s = 0; s < 4; ++s) {
            const int ch = (s << 1) + hi;
            s8v ak0 = *(const s8v*)(Kt + ch * 512 + l31 * 8);
            s0 = __builtin_amdgcn_mfma_f32_32x32x16_bf16(ak0, bq[s], s0, 0, 0, 0);
        }
        if (do1) {
            #pragma unroll
            for (int s = 0; s < 4; ++s) {
                const int ch = (s << 1) + hi;
                s8v ak1 = *(const s8v*)(Kt + ch * 512 + 256 + l31 * 8);
                s1 = __builtin_amdgcn_mfma_f32_32x32x16_bf16(ak1, bq[s], s1, 0, 0, 0);
            }
        }

        // causal mask (diag tile only) + running max
        float mloc = -INFINITY;
        if (diag) {
            #pragma unroll
            for (int r = 0; r < 16; ++r) {
                const int keyb = kt * 64 + (r & 3) + 8 * (r >> 2) + 4 * hi;
                float v0 = (keyb > qg) ? -INFINITY : s0[r];
                s0[r] = v0;
                mloc = fmaxf(mloc, v0);
                if (do1) {
                    float v1 = (keyb + 32 > qg) ? -INFINITY : s1[r];
                    s1[r] = v1;
                    mloc = fmaxf(mloc, v1);
                }
            }
        } else {
            #pragma unroll
            for (int r = 0; r < 16; ++r)
                mloc = fmaxf(mloc, fmaxf(s0[r], s1[r]));
        }
        mloc = fmaxf(mloc, __shfl_xor(mloc, 32));
        const float mnew = fmaxf(mr, mloc);
        const float alpha = EXP2F(mr - mnew);
        mr = mnew;

        // exp2 + row sum + bf16 pack (pairs of consecutive keys)
        float ps = 0.f;
        u32 P0[8], P1[8];
        #pragma unroll
        for (int p = 0; p < 8; ++p) {
            float a0 = EXP2F(s0[2 * p] - mnew), b0 = EXP2F(s0[2 * p + 1] - mnew);
            ps += a0 + b0;
            P0[p] = bfpack(a0, b0);
        }
        if (do1) {
            #pragma unroll
            for (int p = 0; p < 8; ++p) {
                float a1 = EXP2F(s1[2 * p] - mnew), b1 = EXP2F(s1[2 * p + 1] - mnew);
                ps += a1 + b1;
                P1[p] = bfpack(a1, b1);
            }
        }
        ps += __shfl_xor(ps, 32);
        lr = lr * alpha + ps;

        #pragma unroll
        for (int r = 0; r < 16; ++r) { acco0[r] *= alpha; acco1[r] *= alpha; }

        // O^T += V^T P^T.  B-frag(P^T) built in-register: lane half swap.
        const int tmax = do1 ? 2 : 1;
        for (int t = 0; t < tmax; ++t) {
            const u32* pt = t ? P1 : P0;
            #pragma unroll
            for (int ss = 0; ss < 2; ++ss) {
                const int b4 = ss * 4;
                const u32 x0 = __shfl_xor(pt[b4 + 0], 32);
                const u32 x1 = __shfl_xor(pt[b4 + 1], 32);
                const u32 x2 = __shfl_xor(pt[b4 + 2], 32);
                const u32 x3 = __shfl_xor(pt[b4 + 3], 32);
                uint4 fr;
                fr.x = hi ? x2 : pt[b4 + 0];
                fr.y = hi ? x3 : pt[b4 + 1];
                fr.z = hi ? pt[b4 + 2] : x0;
                fr.w = hi ? pt[b4 + 3] : x1;
                const s8v pf = __builtin_bit_cast(s8v, fr);
                const int sg = t * 2 + ss, ch = (sg << 1) + hi;
                s8v av0 = *(const s8v*)(Vt + ch * 512 + l31 * 8);
                s8v av1 = *(const s8v*)(Vt + ch * 512 + 256 + l31 * 8);
                acco0 = __builtin_amdgcn_mfma_f32_32x32x16_bf16(av0, pf, acco0, 0, 0, 0);
                acco1 = __builtin_amdgcn_mfma_f32_32x32x16_bf16(av1, pf, acco1, 0, 0, 0);
            }
        }
    }

    // ---- wave1 deposits partials; wave0 merges (exact flash combine)
    if (w == 1) {
        #pragma unroll
        for (int r = 0; r < 16; ++r) {
            MO[lane * 32 + r] = acco0[r];
            MO[lane * 32 + 16 + r] = acco1[r];
        }
        MS[lane] = mr;
        MS[64 + lane] = lr;
    }
    __syncthreads();
    if (w == 1) return;

    {
        const float m1 = MS[lane], l1 = MS[64 + lane];
        const float m = fmaxf(mr, m1);           // m1 always finite
        const float a0 = EXP2F(mr - m);          // exp2(-inf)=0 when wave0 empty
        const float a1 = EXP2F(m1 - m);
        lr = lr * a0 + l1 * a1;
        #pragma unroll
        for (int r = 0; r < 16; ++r) {
            acco0[r] = acco0[r] * a0 + MO[lane * 32 + r] * a1;
            acco1[r] = acco1[r] * a0 + MO[lane * 32 + 16 + r] * a1;
        }
    }

    // ---- epilogue: wave-private LDS transpose -> coalesced float4 stores
    const float inv = 1.0f / lr;
    #pragma unroll
    for (int r = 0; r < 16; ++r) {
        const int d = (r & 3) + 8 * (r >> 2) + 4 * hi;
        LT[l31 * 68 + d] = acco0[r] * inv;
        LT[l31 * 68 + 32 + d] = acco1[r] * inv;
    }
    const int qr2 = lane >> 4, chk = lane & 15;
    #pragma unroll
    for (int p = 0; p < 8; ++p) {
        const int qrow = p * 4 + qr2;
        f4v v4 = *(const f4v*)&LT[qrow * 68 + chk * 4];
        *(float4*)(Y + (size_t)(b * 2048 + q0 + qrow) * 1024
                   + h * 64 + chk * 4) = (float4){v4[0], v4[1], v4[2], v4[3]};
    }
}

// ---------------------------------------------------------------------------
extern "C" void kernel_launch(void* const* d_in, const int* in_sizes, int n_in,
                              void* d_out, int out_size, void* d_ws,
                              size_t ws_size, hipStream_t stream)
{
    const float* x_qk = (const float*)d_in[0];
    const float* x_v  = (const float*)d_in[1];
    const float* W    = (const float*)d_in[2];
    const float* bias = (const float*)d_in[3];
    float* out = (float*)d_out;

    unsigned char* ws = (unsigned char*)d_ws;
    ush* Wt = (ush*)(ws);                  // 4 MB  [0,4M)
    ush* Vf = (ush*)(ws + (4u << 20));     // 8 MB  [4M,12M)
    ush* Qb = (ush*)(ws + (12u << 20));    // 8 MB  [12M,20M)
    ush* Kf = (ush*)(ws + (20u << 20));    // 8 MB  [20M,28M)

    prep_kernel<<<1536, 256, 0, stream>>>(W, x_v, Wt, Vf);
    gemm_kernel<<<dim3(16, 32), 256, 0, stream>>>(x_qk, Wt, bias, Qb, Kf);
    attn_kernel<<<2048, 128, 0, stream>>>(Qb, Kf, Vf, out);
}